// Round 17
// baseline (7449.425 us; speedup 1.0000x reference)
//
#include <hip/hip_runtime.h>
#include <cstdint>

#define NPTS 32768
#define DIM  256
#define NK   128
#define NITER 100
#define NBLK 256
#define NTHR 1024
#define PAD  33

typedef unsigned short ushort_t;
typedef unsigned long long ull_t;
typedef __attribute__((ext_vector_type(8))) short s8v;   // 8 bf16 in 4 VGPRs
typedef __attribute__((ext_vector_type(4))) float f4v;   // MFMA accumulator

__device__ __forceinline__ unsigned short f2bf(float f) {
  unsigned u = __float_as_uint(f);
  u += 0x7fffu + ((u >> 16) & 1u);      // RTNE
  return (unsigned short)(u >> 16);
}
__device__ __forceinline__ float bf2f(unsigned short b) {
  return __uint_as_float(((unsigned)b) << 16);
}

// agent-scope (LLC-coherent) accesses — bypass non-coherent L1/L2
__device__ __forceinline__ void cstore(float* p, float v) {
  __hip_atomic_store(p, v, __ATOMIC_RELAXED, __HIP_MEMORY_SCOPE_AGENT);
}
__device__ __forceinline__ float cload(const float* p) {
  return __hip_atomic_load(p, __ATOMIC_RELAXED, __HIP_MEMORY_SCOPE_AGENT);
}
__device__ __forceinline__ void cstorei(int* p, int v) {
  __hip_atomic_store(p, v, __ATOMIC_RELAXED, __HIP_MEMORY_SCOPE_AGENT);
}
__device__ __forceinline__ int cloadi(const int* p) {
  return __hip_atomic_load(p, __ATOMIC_RELAXED, __HIP_MEMORY_SCOPE_AGENT);
}
__device__ __forceinline__ void cstore64(ull_t* p, ull_t v) {
  __hip_atomic_store(p, v, __ATOMIC_RELAXED, __HIP_MEMORY_SCOPE_AGENT);
}

// ---- aggregated 2-hop grid barrier, fence-free (proven R14/R15) ----
__device__ __forceinline__ void gbar(unsigned* flags, unsigned* grep, unsigned gen) {
  __syncthreads();                        // drain all vmem (cstores visible)
  if (threadIdx.x == 0)
    __hip_atomic_store(&flags[blockIdx.x * 16], gen, __ATOMIC_RELAXED, __HIP_MEMORY_SCOPE_AGENT);
  if (blockIdx.x == 0) {
    if (threadIdx.x < NBLK) {
      while (__hip_atomic_load(&flags[threadIdx.x * 16], __ATOMIC_RELAXED, __HIP_MEMORY_SCOPE_AGENT) < gen)
        __builtin_amdgcn_s_sleep(2);
    }
    __syncthreads();                      // all 256 arrivals observed
    if (threadIdx.x < 64)
      __hip_atomic_store(&grep[threadIdx.x * 16], gen, __ATOMIC_RELAXED, __HIP_MEMORY_SCOPE_AGENT);
  }
  if (threadIdx.x == 0) {
    while (__hip_atomic_load(&grep[(blockIdx.x & 63) * 16], __ATOMIC_RELAXED, __HIP_MEMORY_SCOPE_AGENT) < gen)
      __builtin_amdgcn_s_sleep(2);
  }
  __syncthreads();
  asm volatile("" ::: "memory");
  __syncthreads();
}

union StU {                 // phase-exclusive LDS scratch (20.5 KB)
  struct { char ch[128 * 80]; char cl[128 * 80]; } a;       // GEMM C-eighth tiles (padded rows)
  struct { float accB[NK * PAD]; ushort_t idsl16[1024]; } b;
  struct { float red4[1024]; float redcn[1024]; } c;
};

// 16-wave (4x4) 3-pass hi/lo bf16 MFMA GEMM over 8 D-eighths (32 dims each).
// A-operand: resident swizzled LDS x-image. B-operand: VERSIONED cpk,
// register-batch-prefetched (4-eighth lookahead) so the 8 per-eighth LLC
// round-trips collapse to ~1 exposed latency.
__device__ __forceinline__ void gemm_core(
    const s8v* __restrict__ xhR, const s8v* __restrict__ xlR,
    StU& u, float* cns, int t,
    const ull_t* __restrict__ cpk, const float* __restrict__ cn2, f4v (&acc)[2][2]) {
  const int lane = t & 63;
  const int w    = t >> 6;
  const int wr   = w >> 2, wc = w & 3;    // 4x4 wave grid
  const int g    = lane >> 4, lr = lane & 15;

  if (t < NK) cns[t] = cload(&cn2[2 * t]) + cload(&cn2[2 * t + 1]);

  const f4v zero = {0.f, 0.f, 0.f, 0.f};
#pragma unroll
  for (int i = 0; i < 2; ++i)
#pragma unroll
    for (int j = 0; j < 2; ++j) acc[i][j] = zero;

  // staging role (waves 0-7): row = cluster, cc = 8-dim granule within eighth
  const int srow = t >> 2, scc = t & 3;
  const ull_t* sbase = cpk + (size_t)srow * 128 + scc * 4;
  ull_t wreg[4][4];
  if (t < 512) {                          // batch-prefetch eighths 0..3
#pragma unroll
    for (int q = 0; q < 4; ++q) {
      const ull_t* s2 = sbase + q * 16;
      wreg[q][0] = s2[0]; wreg[q][1] = s2[1]; wreg[q][2] = s2[2]; wreg[q][3] = s2[3];
    }
  }

#pragma unroll
  for (int q = 0; q < 8; ++q) {           // eighths: dims q*32..q*32+31
    if (t < 512) {                        // unpack this eighth from regs
      ull_t w0 = wreg[q & 3][0], w1 = wreg[q & 3][1];
      ull_t w2 = wreg[q & 3][2], w3 = wreg[q & 3][3];
      s8v vh, vl;
      vh[0] = (short)w0; vl[0] = (short)(w0 >> 16); vh[1] = (short)(w0 >> 32); vl[1] = (short)(w0 >> 48);
      vh[2] = (short)w1; vl[2] = (short)(w1 >> 16); vh[3] = (short)(w1 >> 32); vl[3] = (short)(w1 >> 48);
      vh[4] = (short)w2; vl[4] = (short)(w2 >> 16); vh[5] = (short)(w2 >> 32); vl[5] = (short)(w2 >> 48);
      vh[6] = (short)w3; vl[6] = (short)(w3 >> 16); vh[7] = (short)(w3 >> 32); vl[7] = (short)(w3 >> 48);
      *(s8v*)(u.a.ch + srow * 80 + scc * 16) = vh;
      *(s8v*)(u.a.cl + srow * 80 + scc * 16) = vl;
      if (q < 4) {                        // refill slot with eighth q+4
        const ull_t* s2 = sbase + (q + 4) * 16;
        wreg[q & 3][0] = s2[0]; wreg[q & 3][1] = s2[1];
        wreg[q & 3][2] = s2[2]; wreg[q & 3][3] = s2[3];
      }
    }
    __syncthreads();                      // stage landed; prev eighth reads done
    s8v ah[2], al[2], bh[2], bl[2];
#pragma unroll
    for (int i = 0; i < 2; ++i) {
      int ra = wr * 32 + i * 16 + lr;
      int o = ra * 512 + (((q * 4 + g) ^ (lr & 7)) * 16);
      ah[i] = *(const s8v*)((const char*)xhR + o);
      al[i] = *(const s8v*)((const char*)xlR + o);
    }
#pragma unroll
    for (int j = 0; j < 2; ++j) {
      int rb = wc * 32 + j * 16 + lr;
      int o = rb * 80 + g * 16;
      bh[j] = *(const s8v*)(u.a.ch + o);
      bl[j] = *(const s8v*)(u.a.cl + o);
    }
#pragma unroll
    for (int i = 0; i < 2; ++i)
#pragma unroll
      for (int j = 0; j < 2; ++j) {
        acc[i][j] = __builtin_amdgcn_mfma_f32_16x16x32_bf16(ah[i], bh[j], acc[i][j], 0, 0, 0);
        acc[i][j] = __builtin_amdgcn_mfma_f32_16x16x32_bf16(ah[i], bl[j], acc[i][j], 0, 0, 0);
        acc[i][j] = __builtin_amdgcn_mfma_f32_16x16x32_bf16(al[i], bh[j], acc[i][j], 0, 0, 0);
      }
    __syncthreads();                      // reads done before next stage
  }
}

__global__ __launch_bounds__(NTHR, 1) void kmeans_fused(
    const float* __restrict__ x, const int* __restrict__ init_idx,
    ull_t* __restrict__ cpkv, float* __restrict__ cn2v, int* __restrict__ ids,
    float* __restrict__ psum, float* __restrict__ pcnt,
    float* __restrict__ outp, unsigned* __restrict__ flags,
    unsigned* __restrict__ grep, float* __restrict__ out) {
  __shared__ s8v xhR[4096];               // 64 KB resident swizzled XH image
  __shared__ s8v xlR[4096];               // 64 KB resident swizzled XL image
  __shared__ StU u;
  __shared__ float cns[NK];
  __shared__ float redd[NK * 4];
  __shared__ int   redk[NK * 4];
  __shared__ float gmaxs[NK];
  __shared__ float labvs[NK];
  __shared__ int   labis[NK];
  __shared__ int   cntB[NK];
  __shared__ ushort_t hsm[DIM], lsm[DIM];
  __shared__ float cntsh;

  const int b = blockIdx.x;
  const int t = threadIdx.x;
  const int lane = t & 63;
  const int w  = t >> 6;
  const int wr = w >> 2, wc = w & 3;
  const int g  = lane >> 4, lr = lane & 15;
  const int pbase = b * 128;
  unsigned gen = 1;

  // ---------------- prep: own 128-pt tile -> resident hi/lo LDS image ----------------
  for (int i = 0; i < 4; ++i) {
    int G = i * NTHR + t;                 // granule [0,4096): row = pt, c = 8-dim granule
    int row = G >> 5, c = G & 31;
    const float4* src = (const float4*)(x + ((size_t)pbase + row) * DIM + c * 8);
    float4 fa = src[0], fb = src[1];
    float vv[8] = {fa.x, fa.y, fa.z, fa.w, fb.x, fb.y, fb.z, fb.w};
    s8v vh, vl;
#pragma unroll
    for (int j = 0; j < 8; ++j) {
      unsigned short hh = f2bf(vv[j]);
      vh[j] = (short)hh;
      vl[j] = (short)f2bf(vv[j] - bf2f(hh));
    }
    int pos = c ^ (row & 7);
    *(s8v*)((char*)xhR + row * 512 + pos * 16) = vh;
    *(s8v*)((char*)xlR + row * 512 + pos * 16) = vl;
  }

  // ---------------- init: c0 = x[init_idx] -> packed image v0 + cn2 v0 ----------------
  if (b < NK) {
    float eff = 0.f;
    if (t < DIM) {
      float v = x[init_idx[b] * DIM + t];
      unsigned short hh = f2bf(v);
      unsigned short ll = f2bf(v - bf2f(hh));
      hsm[t] = hh; lsm[t] = ll;
      eff = bf2f(hh) + bf2f(ll);
    }
    __syncthreads();
    u.c.redcn[t] = (t < DIM) ? eff * eff : 0.f;
    if (t < NK) {
      ull_t wv = (ull_t)hsm[2 * t] | ((ull_t)lsm[2 * t] << 16)
               | ((ull_t)hsm[2 * t + 1] << 32) | ((ull_t)lsm[2 * t + 1] << 48);
      cstore64(&cpkv[(size_t)b * 128 + t], wv);
    }
    __syncthreads();
    for (int s = 512; s > 0; s >>= 1) { if (t < s) u.c.redcn[t] += u.c.redcn[t + s]; __syncthreads(); }
    if (t == 0) { cstore(&cn2v[b * 2], u.c.redcn[0]); cstore(&cn2v[b * 2 + 1], 0.f); }
  }
  gbar(flags, grep, gen); ++gen;
  // one-time L2/L1 invalidate: clears any harness-poison (0xAA) lines cached
  // for ws addresses. After this, freshness comes from versioned addresses
  // (within launch) and determinism (across graph replays).
  if (t == 0) __threadfence();
  __syncthreads();

  // ---------------- main loop: A -> B -> C ----------------
  for (int it = 0; it < NITER; ++it) {
    const ull_t*  cpkR = cpkv + (size_t)it * (NK * 128);
    const float*  cn2R = cn2v + (size_t)it * (NK * 2);
    ull_t* cpkW = cpkv + (size_t)(it + 1) * (NK * 128);
    float* cn2W = cn2v + (size_t)(it + 1) * (NK * 2);

    // ---- phase A: assign; ids -> LLC ----
    {
      f4v acc[2][2];
      gemm_core(xhR, xlR, u, cns, t, cpkR, cn2R, acc);
#pragma unroll
      for (int i = 0; i < 2; ++i) {
#pragma unroll
        for (int r = 0; r < 4; ++r) {
          int prow = wr * 32 + i * 16 + g * 4 + r;
          float bd = 1e30f; int bk = 0;
#pragma unroll
          for (int j = 0; j < 2; ++j) {
            int col = wc * 32 + j * 16 + lr;
            float s = cns[col] - 2.f * acc[i][j][r];
            if (s < bd || (s == bd && col < bk)) { bd = s; bk = col; }
          }
#pragma unroll
          for (int msk = 1; msk < 16; msk <<= 1) {
            float od = __shfl_xor(bd, msk, 64);
            int   ok = __shfl_xor(bk, msk, 64);
            if (od < bd || (od == bd && ok < bk)) { bd = od; bk = ok; }
          }
          if (lr == 0) { redd[prow * 4 + wc] = bd; redk[prow * 4 + wc] = bk; }
        }
      }
      __syncthreads();
      if (t < NK) {
        float bd = redd[t * 4]; int bk = redk[t * 4];
#pragma unroll
        for (int q = 1; q < 4; ++q) {
          float dq = redd[t * 4 + q]; int kq = redk[t * 4 + q];
          if (dq < bd || (dq == bd && kq < bk)) { bd = dq; bk = kq; }
        }
        cstorei(&ids[pbase + t], bk);
      }
    }
    gbar(flags, grep, gen); ++gen;

    // ---- phase B: D-split segment-sum (32 pgroups x 8 dgroups), L2-resident x ----
    {
      const int pg = b & 31, dg = b >> 5;
      for (int i = t; i < NK * PAD; i += NTHR) u.b.accB[i] = 0.f;
      if (t < NK) cntB[t] = 0;
      u.b.idsl16[t] = (ushort_t)cloadi(&ids[pg * 1024 + t]);
      __syncthreads();
      const int id = u.b.idsl16[t];
      if (dg == 0) atomicAdd(&cntB[id], 1);
      // NORMAL loads of immutable x: fixed 128KB slice per block -> L2-resident
      const float4* xr = (const float4*)(x + ((size_t)pg * 1024 + t) * DIM + dg * 32);
      float4 v0 = xr[0], v1 = xr[1], v2 = xr[2], v3 = xr[3];
      float4 v4 = xr[4], v5 = xr[5], v6 = xr[6], v7 = xr[7];
      float* ab = &u.b.accB[id * PAD];
      atomicAdd(ab + 0,  v0.x); atomicAdd(ab + 1,  v0.y); atomicAdd(ab + 2,  v0.z); atomicAdd(ab + 3,  v0.w);
      atomicAdd(ab + 4,  v1.x); atomicAdd(ab + 5,  v1.y); atomicAdd(ab + 6,  v1.z); atomicAdd(ab + 7,  v1.w);
      atomicAdd(ab + 8,  v2.x); atomicAdd(ab + 9,  v2.y); atomicAdd(ab + 10, v2.z); atomicAdd(ab + 11, v2.w);
      atomicAdd(ab + 12, v3.x); atomicAdd(ab + 13, v3.y); atomicAdd(ab + 14, v3.z); atomicAdd(ab + 15, v3.w);
      atomicAdd(ab + 16, v4.x); atomicAdd(ab + 17, v4.y); atomicAdd(ab + 18, v4.z); atomicAdd(ab + 19, v4.w);
      atomicAdd(ab + 20, v5.x); atomicAdd(ab + 21, v5.y); atomicAdd(ab + 22, v5.z); atomicAdd(ab + 23, v5.w);
      atomicAdd(ab + 24, v6.x); atomicAdd(ab + 25, v6.y); atomicAdd(ab + 26, v6.z); atomicAdd(ab + 27, v6.w);
      atomicAdd(ab + 28, v7.x); atomicAdd(ab + 29, v7.y); atomicAdd(ab + 30, v7.z); atomicAdd(ab + 31, v7.w);
      __syncthreads();
#pragma unroll
      for (int s2 = 0; s2 < 4; ++s2) {
        int idx = s2 * NTHR + t;          // [0,4096)
        int k2 = idx >> 5, dl = idx & 31;
        cstore(&psum[(((size_t)dg * NK + k2) * 32 + pg) * 32 + dl], u.b.accB[k2 * PAD + dl]);
      }
      if (dg == 0 && t < NK)
        cstore(&pcnt[(size_t)pg * NK + t], (float)cntB[t]);
    }
    gbar(flags, grep, gen); ++gen;

    // ---- phase C: 256 blocks = 128 clusters x 2 D-halves -> version it+1 ----
    {
      const int k = b >> 1, hh2 = b & 1;
      const int dwh = t & 127, pch = t >> 7;   // dim-in-half [0,128), pgroup chunk [0,8)
      const int dgc = hh2 * 4 + (dwh >> 5), dlc = dwh & 31;
      float s = 0.f;
#pragma unroll
      for (int p2 = pch * 4; p2 < pch * 4 + 4; ++p2)
        s += cload(&psum[(((size_t)dgc * NK + k) * 32 + p2) * 32 + dlc]);
      u.c.red4[pch * 128 + dwh] = s;
      float cv = (t < 32) ? cload(&pcnt[(size_t)t * NK + k]) : 0.f;
      if (t < 64) {
#pragma unroll
        for (int m = 1; m < 32; m <<= 1) cv += __shfl_xor(cv, m, 64);
      }
      if (t == 0) cntsh = cv;
      __syncthreads();
      float eff = 0.f;
      if (t < 128) {
        float ssum = 0.f;
#pragma unroll
        for (int ww = 0; ww < 8; ++ww) ssum += u.c.red4[ww * 128 + t];
        float mean = ssum / cntsh;        // NaN if empty, as ref
        unsigned short hh = f2bf(mean);
        unsigned short ll = f2bf(mean - bf2f(hh));
        hsm[t] = hh; lsm[t] = ll;
        eff = bf2f(hh) + bf2f(ll);
      }
      __syncthreads();                    // red4 reads + hsm/lsm writes done
      u.c.redcn[t] = (t < 128) ? eff * eff : 0.f;
      if (t < 64) {
        ull_t wv = (ull_t)hsm[2 * t] | ((ull_t)lsm[2 * t] << 16)
                 | ((ull_t)hsm[2 * t + 1] << 32) | ((ull_t)lsm[2 * t + 1] << 48);
        cstore64(&cpkW[(size_t)k * 128 + hh2 * 64 + t], wv);
      }
      __syncthreads();
      for (int st = 512; st > 0; st >>= 1) { if (t < st) u.c.redcn[t] += u.c.redcn[t + st]; __syncthreads(); }
      if (t == 0) cstore(&cn2W[k * 2 + hh2], u.c.redcn[0]);
    }
    gbar(flags, grep, gen); ++gen;
  }

  // ---------------- final: loss (log-softmax + CE), deterministic reduce ----------------
  {
    f4v acc[2][2];
    gemm_core(xhR, xlR, u, cns, t,
              cpkv + (size_t)NITER * (NK * 128), cn2v + (size_t)NITER * (NK * 2), acc);
#pragma unroll
    for (int i = 0; i < 2; ++i) {
#pragma unroll
      for (int r = 0; r < 4; ++r) {
        int prow = wr * 32 + i * 16 + g * 4 + r;
        float m = -1e30f;
#pragma unroll
        for (int j = 0; j < 2; ++j) m = fmaxf(m, acc[i][j][r]);
#pragma unroll
        for (int msk = 1; msk < 16; msk <<= 1) m = fmaxf(m, __shfl_xor(m, msk, 64));
        if (lr == 0) redd[prow * 4 + wc] = m;
      }
    }
    __syncthreads();
    if (t < NK) {
      float m = redd[t * 4];
#pragma unroll
      for (int q = 1; q < 4; ++q) m = fmaxf(m, redd[t * 4 + q]);
      gmaxs[t] = m;
      labis[t] = cloadi(&ids[pbase + t]);
    }
    __syncthreads();
#pragma unroll
    for (int i = 0; i < 2; ++i) {
#pragma unroll
      for (int r = 0; r < 4; ++r) {
        int prow = wr * 32 + i * 16 + g * 4 + r;
        float m = gmaxs[prow];
        int lab = labis[prow];
        float s = 0.f;
#pragma unroll
        for (int j = 0; j < 2; ++j) {
          int col = wc * 32 + j * 16 + lr;
          float v = acc[i][j][r];
          s += expf(v - m);
          if (col == lab) labvs[prow] = v;
        }
#pragma unroll
        for (int msk = 1; msk < 16; msk <<= 1) s += __shfl_xor(s, msk, 64);
        if (lr == 0) redd[prow * 4 + wc] = s;
      }
    }
    __syncthreads();
    if (t < NK) {
      float se = redd[t * 4] + redd[t * 4 + 1] + redd[t * 4 + 2] + redd[t * 4 + 3];
      float lse = gmaxs[t] + logf(se);
      gmaxs[t] = lse - labvs[t];
    }
    __syncthreads();
    if (t == 0) {
      float tot = 0.f;
      for (int q = 0; q < NK; ++q) tot += gmaxs[q];
      cstore(&outp[b], tot);
    }
  }
  gbar(flags, grep, gen); ++gen;
  if (b == 0) {
    u.c.redcn[t] = (t < NBLK) ? cload(&outp[t]) : 0.f;
    __syncthreads();
    for (int s = 512; s > 0; s >>= 1) { if (t < s) u.c.redcn[t] += u.c.redcn[t + s]; __syncthreads(); }
    if (t == 0) out[0] = u.c.redcn[0] * (1.0f / (float)NPTS);
  }
}

extern "C" void kernel_launch(void* const* d_in, const int* in_sizes, int n_in,
                              void* d_out, int out_size, void* d_ws, size_t ws_size,
                              hipStream_t stream) {
  const float* x        = (const float*)d_in[0];
  const int*   init_idx = (const int*)d_in[1];
  float* out = (float*)d_out;
  char* ws = (char*)d_ws;

  // ws layout (bytes):
  ull_t* cpkv = (ull_t*)(ws);                         // 101 * 131072 = 13238272
  float* cn2v = (float*)(ws + 13238272);              // 101 * 1024 = 103424
  int*   ids  = (int*)(ws + 13341696);                // 131072
  float* psum = (float*)(ws + 13472768);              // 8*128*32*32*4 = 4194304
  float* pcnt = (float*)(ws + 17667072);              // 32*128*4 = 16384
  float* outp = (float*)(ws + 17683456);              // 1024
  unsigned* flags = (unsigned*)(ws + 17684480);       // 256*64B = 16384
  unsigned* grep  = (unsigned*)(ws + 17700864);       // 64*64B = 4096

  // reset barrier state every launch (graph replays include this node)
  hipMemsetAsync(flags, 0, 20480, stream);
  kmeans_fused<<<dim3(NBLK), dim3(NTHR), 0, stream>>>(
      x, init_idx, cpkv, cn2v, ids, psum, pcnt, outp, flags, grep, out);
}

// Round 18
// 6866.712 us; speedup vs baseline: 1.0849x; 1.0849x over previous
//
#include <hip/hip_runtime.h>
#include <cstdint>

#define NPTS 32768
#define DIM  256
#define NK   128
#define NITER 100
#define NBLK 256
#define NTHR 1024
#define PAD  33

typedef unsigned short ushort_t;
typedef unsigned long long ull_t;
typedef __attribute__((ext_vector_type(8))) short s8v;   // 8 bf16 in 4 VGPRs
typedef __attribute__((ext_vector_type(4))) float f4v;   // MFMA accumulator

__device__ __forceinline__ unsigned short f2bf(float f) {
  unsigned u = __float_as_uint(f);
  u += 0x7fffu + ((u >> 16) & 1u);      // RTNE
  return (unsigned short)(u >> 16);
}
__device__ __forceinline__ float bf2f(unsigned short b) {
  return __uint_as_float(((unsigned)b) << 16);
}

// agent-scope (LLC-coherent) accesses — bypass non-coherent L1/L2
__device__ __forceinline__ void cstore(float* p, float v) {
  __hip_atomic_store(p, v, __ATOMIC_RELAXED, __HIP_MEMORY_SCOPE_AGENT);
}
__device__ __forceinline__ float cload(const float* p) {
  return __hip_atomic_load(p, __ATOMIC_RELAXED, __HIP_MEMORY_SCOPE_AGENT);
}
__device__ __forceinline__ void cstorei(int* p, int v) {
  __hip_atomic_store(p, v, __ATOMIC_RELAXED, __HIP_MEMORY_SCOPE_AGENT);
}
__device__ __forceinline__ int cloadi(const int* p) {
  return __hip_atomic_load(p, __ATOMIC_RELAXED, __HIP_MEMORY_SCOPE_AGENT);
}
__device__ __forceinline__ void cstore64(ull_t* p, ull_t v) {
  __hip_atomic_store(p, v, __ATOMIC_RELAXED, __HIP_MEMORY_SCOPE_AGENT);
}

// ---- aggregated 2-hop grid barrier, fence-free (proven R14/R15) ----
__device__ __forceinline__ void gbar(unsigned* flags, unsigned* grep, unsigned gen) {
  __syncthreads();                        // drain all vmem (cstores visible)
  if (threadIdx.x == 0)
    __hip_atomic_store(&flags[blockIdx.x * 16], gen, __ATOMIC_RELAXED, __HIP_MEMORY_SCOPE_AGENT);
  if (blockIdx.x == 0) {
    if (threadIdx.x < NBLK) {
      while (__hip_atomic_load(&flags[threadIdx.x * 16], __ATOMIC_RELAXED, __HIP_MEMORY_SCOPE_AGENT) < gen)
        __builtin_amdgcn_s_sleep(2);
    }
    __syncthreads();                      // all 256 arrivals observed
    if (threadIdx.x < 64)
      __hip_atomic_store(&grep[threadIdx.x * 16], gen, __ATOMIC_RELAXED, __HIP_MEMORY_SCOPE_AGENT);
  }
  if (threadIdx.x == 0) {
    while (__hip_atomic_load(&grep[(blockIdx.x & 63) * 16], __ATOMIC_RELAXED, __HIP_MEMORY_SCOPE_AGENT) < gen)
      __builtin_amdgcn_s_sleep(2);
  }
  __syncthreads();
  asm volatile("" ::: "memory");
  __syncthreads();
}

union StU {                 // phase-exclusive LDS scratch (20.5 KB)
  struct { char ch[128 * 80]; char cl[128 * 80]; } a;       // GEMM C-eighth tiles (padded rows)
  struct { float accB[NK * PAD]; ushort_t idsl16[1024]; } b;
  struct { float red4[1024]; float redcn[1024]; } c;
};

// 16-wave (4x4) 3-pass hi/lo bf16 MFMA GEMM over 8 D-eighths (32 dims each).
// A-operand: resident swizzled LDS x-image. B-operand: VERSIONED cpk staged
// per eighth via NORMAL loads — fresh addresses every iteration, so no stale
// L2 lines and no fences needed.
__device__ __forceinline__ void gemm_core(
    const s8v* __restrict__ xhR, const s8v* __restrict__ xlR,
    StU& u, float* cns, int t,
    const ull_t* __restrict__ cpk, const float* __restrict__ cn2, f4v (&acc)[2][2]) {
  const int lane = t & 63;
  const int w    = t >> 6;
  const int wr   = w >> 2, wc = w & 3;    // 4x4 wave grid
  const int g    = lane >> 4, lr = lane & 15;

  if (t < NK) cns[t] = cload(&cn2[2 * t]) + cload(&cn2[2 * t + 1]);

  const f4v zero = {0.f, 0.f, 0.f, 0.f};
#pragma unroll
  for (int i = 0; i < 2; ++i)
#pragma unroll
    for (int j = 0; j < 2; ++j) acc[i][j] = zero;

  for (int q = 0; q < 8; ++q) {           // eighths: dims q*32..q*32+31
    if (t < 512) {                        // stage CH/CL eighth (normal loads)
      int row = t >> 2, c = t & 3;        // row=cluster, c=granule (8 dims)
      const ull_t* src = cpk + (size_t)row * 128 + q * 16 + c * 4;
      ull_t w0 = src[0], w1 = src[1], w2 = src[2], w3 = src[3];
      s8v vh, vl;
      vh[0] = (short)w0; vl[0] = (short)(w0 >> 16); vh[1] = (short)(w0 >> 32); vl[1] = (short)(w0 >> 48);
      vh[2] = (short)w1; vl[2] = (short)(w1 >> 16); vh[3] = (short)(w1 >> 32); vl[3] = (short)(w1 >> 48);
      vh[4] = (short)w2; vl[4] = (short)(w2 >> 16); vh[5] = (short)(w2 >> 32); vl[5] = (short)(w2 >> 48);
      vh[6] = (short)w3; vl[6] = (short)(w3 >> 16); vh[7] = (short)(w3 >> 32); vl[7] = (short)(w3 >> 48);
      *(s8v*)(u.a.ch + row * 80 + c * 16) = vh;
      *(s8v*)(u.a.cl + row * 80 + c * 16) = vl;
    }
    __syncthreads();                      // stage landed; prev eighth reads done
    s8v ah[2], al[2], bh[2], bl[2];
#pragma unroll
    for (int i = 0; i < 2; ++i) {
      int ra = wr * 32 + i * 16 + lr;
      int o = ra * 512 + (((q * 4 + g) ^ (lr & 7)) * 16);
      ah[i] = *(const s8v*)((const char*)xhR + o);
      al[i] = *(const s8v*)((const char*)xlR + o);
    }
#pragma unroll
    for (int j = 0; j < 2; ++j) {
      int rb = wc * 32 + j * 16 + lr;
      int o = rb * 80 + g * 16;
      bh[j] = *(const s8v*)(u.a.ch + o);
      bl[j] = *(const s8v*)(u.a.cl + o);
    }
#pragma unroll
    for (int i = 0; i < 2; ++i)
#pragma unroll
      for (int j = 0; j < 2; ++j) {
        acc[i][j] = __builtin_amdgcn_mfma_f32_16x16x32_bf16(ah[i], bh[j], acc[i][j], 0, 0, 0);
        acc[i][j] = __builtin_amdgcn_mfma_f32_16x16x32_bf16(ah[i], bl[j], acc[i][j], 0, 0, 0);
        acc[i][j] = __builtin_amdgcn_mfma_f32_16x16x32_bf16(al[i], bh[j], acc[i][j], 0, 0, 0);
      }
    __syncthreads();                      // reads done before next stage
  }
}

__global__ __launch_bounds__(NTHR, 1) void kmeans_fused(
    const float* __restrict__ x, const int* __restrict__ init_idx,
    ull_t* __restrict__ cpkv, float* __restrict__ cn2v, int* __restrict__ ids,
    float* __restrict__ psum, float* __restrict__ pcnt,
    float* __restrict__ outp, unsigned* __restrict__ flags,
    unsigned* __restrict__ grep, float* __restrict__ out) {
  __shared__ s8v xhR[4096];               // 64 KB resident swizzled XH image
  __shared__ s8v xlR[4096];               // 64 KB resident swizzled XL image
  __shared__ StU u;
  __shared__ float cns[NK];
  __shared__ float redd[NK * 4];
  __shared__ int   redk[NK * 4];
  __shared__ float gmaxs[NK];
  __shared__ float labvs[NK];
  __shared__ int   labis[NK];
  __shared__ int   cntB[NK];
  __shared__ ushort_t hsm[DIM], lsm[DIM];
  __shared__ float cntsh;

  const int b = blockIdx.x;
  const int t = threadIdx.x;
  const int lane = t & 63;
  const int w  = t >> 6;
  const int wr = w >> 2, wc = w & 3;
  const int g  = lane >> 4, lr = lane & 15;
  const int pbase = b * 128;
  unsigned gen = 1;

  // ---------------- prep: own 128-pt tile -> resident hi/lo LDS image ----------------
  for (int i = 0; i < 4; ++i) {
    int G = i * NTHR + t;                 // granule [0,4096): row = pt, c = 8-dim granule
    int row = G >> 5, c = G & 31;
    const float4* src = (const float4*)(x + ((size_t)pbase + row) * DIM + c * 8);
    float4 fa = src[0], fb = src[1];
    float vv[8] = {fa.x, fa.y, fa.z, fa.w, fb.x, fb.y, fb.z, fb.w};
    s8v vh, vl;
#pragma unroll
    for (int j = 0; j < 8; ++j) {
      unsigned short hh = f2bf(vv[j]);
      vh[j] = (short)hh;
      vl[j] = (short)f2bf(vv[j] - bf2f(hh));
    }
    int pos = c ^ (row & 7);
    *(s8v*)((char*)xhR + row * 512 + pos * 16) = vh;
    *(s8v*)((char*)xlR + row * 512 + pos * 16) = vl;
  }

  // ---------------- init: c0 = x[init_idx] -> packed image v0 + cn2 v0 ----------------
  if (b < NK) {
    float eff = 0.f;
    if (t < DIM) {
      float v = x[init_idx[b] * DIM + t];
      unsigned short hh = f2bf(v);
      unsigned short ll = f2bf(v - bf2f(hh));
      hsm[t] = hh; lsm[t] = ll;
      eff = bf2f(hh) + bf2f(ll);
    }
    __syncthreads();
    u.c.redcn[t] = (t < DIM) ? eff * eff : 0.f;
    if (t < NK) {
      ull_t wv = (ull_t)hsm[2 * t] | ((ull_t)lsm[2 * t] << 16)
               | ((ull_t)hsm[2 * t + 1] << 32) | ((ull_t)lsm[2 * t + 1] << 48);
      cstore64(&cpkv[(size_t)b * 128 + t], wv);
    }
    __syncthreads();
    for (int s = 512; s > 0; s >>= 1) { if (t < s) u.c.redcn[t] += u.c.redcn[t + s]; __syncthreads(); }
    if (t == 0) { cstore(&cn2v[b * 2], u.c.redcn[0]); cstore(&cn2v[b * 2 + 1], 0.f); }
  }
  gbar(flags, grep, gen); ++gen;
  // one-time L2/L1 invalidate: clears any harness-poison (0xAA) lines cached
  // for ws addresses. After this, freshness comes from versioned addresses
  // (within launch) and determinism (across graph replays).
  if (t == 0) __threadfence();
  __syncthreads();

  // ---------------- main loop: A -> B -> C ----------------
  for (int it = 0; it < NITER; ++it) {
    const ull_t*  cpkR = cpkv + (size_t)it * (NK * 128);
    const float*  cn2R = cn2v + (size_t)it * (NK * 2);
    ull_t* cpkW = cpkv + (size_t)(it + 1) * (NK * 128);
    float* cn2W = cn2v + (size_t)(it + 1) * (NK * 2);

    // ---- phase A: assign; ids -> LLC ----
    {
      f4v acc[2][2];
      gemm_core(xhR, xlR, u, cns, t, cpkR, cn2R, acc);
#pragma unroll
      for (int i = 0; i < 2; ++i) {
#pragma unroll
        for (int r = 0; r < 4; ++r) {
          int prow = wr * 32 + i * 16 + g * 4 + r;
          float bd = 1e30f; int bk = 0;
#pragma unroll
          for (int j = 0; j < 2; ++j) {
            int col = wc * 32 + j * 16 + lr;
            float s = cns[col] - 2.f * acc[i][j][r];
            if (s < bd || (s == bd && col < bk)) { bd = s; bk = col; }
          }
#pragma unroll
          for (int msk = 1; msk < 16; msk <<= 1) {
            float od = __shfl_xor(bd, msk, 64);
            int   ok = __shfl_xor(bk, msk, 64);
            if (od < bd || (od == bd && ok < bk)) { bd = od; bk = ok; }
          }
          if (lr == 0) { redd[prow * 4 + wc] = bd; redk[prow * 4 + wc] = bk; }
        }
      }
      __syncthreads();
      if (t < NK) {
        float bd = redd[t * 4]; int bk = redk[t * 4];
#pragma unroll
        for (int q = 1; q < 4; ++q) {
          float dq = redd[t * 4 + q]; int kq = redk[t * 4 + q];
          if (dq < bd || (dq == bd && kq < bk)) { bd = dq; bk = kq; }
        }
        cstorei(&ids[pbase + t], bk);
      }
    }
    gbar(flags, grep, gen); ++gen;

    // ---- phase B: D-split segment-sum (32 pgroups x 8 dgroups), L2-resident x ----
    {
      const int pg = b & 31, dg = b >> 5;
      for (int i = t; i < NK * PAD; i += NTHR) u.b.accB[i] = 0.f;
      if (t < NK) cntB[t] = 0;
      u.b.idsl16[t] = (ushort_t)cloadi(&ids[pg * 1024 + t]);
      __syncthreads();
      const int id = u.b.idsl16[t];
      if (dg == 0) atomicAdd(&cntB[id], 1);
      // NORMAL loads of immutable x: fixed 128KB slice per block -> L2-resident
      const float4* xr = (const float4*)(x + ((size_t)pg * 1024 + t) * DIM + dg * 32);
      float4 v0 = xr[0], v1 = xr[1], v2 = xr[2], v3 = xr[3];
      float4 v4 = xr[4], v5 = xr[5], v6 = xr[6], v7 = xr[7];
      float* ab = &u.b.accB[id * PAD];
      atomicAdd(ab + 0,  v0.x); atomicAdd(ab + 1,  v0.y); atomicAdd(ab + 2,  v0.z); atomicAdd(ab + 3,  v0.w);
      atomicAdd(ab + 4,  v1.x); atomicAdd(ab + 5,  v1.y); atomicAdd(ab + 6,  v1.z); atomicAdd(ab + 7,  v1.w);
      atomicAdd(ab + 8,  v2.x); atomicAdd(ab + 9,  v2.y); atomicAdd(ab + 10, v2.z); atomicAdd(ab + 11, v2.w);
      atomicAdd(ab + 12, v3.x); atomicAdd(ab + 13, v3.y); atomicAdd(ab + 14, v3.z); atomicAdd(ab + 15, v3.w);
      atomicAdd(ab + 16, v4.x); atomicAdd(ab + 17, v4.y); atomicAdd(ab + 18, v4.z); atomicAdd(ab + 19, v4.w);
      atomicAdd(ab + 20, v5.x); atomicAdd(ab + 21, v5.y); atomicAdd(ab + 22, v5.z); atomicAdd(ab + 23, v5.w);
      atomicAdd(ab + 24, v6.x); atomicAdd(ab + 25, v6.y); atomicAdd(ab + 26, v6.z); atomicAdd(ab + 27, v6.w);
      atomicAdd(ab + 28, v7.x); atomicAdd(ab + 29, v7.y); atomicAdd(ab + 30, v7.z); atomicAdd(ab + 31, v7.w);
      __syncthreads();
#pragma unroll
      for (int s2 = 0; s2 < 4; ++s2) {
        int idx = s2 * NTHR + t;          // [0,4096)
        int k2 = idx >> 5, dl = idx & 31;
        cstore(&psum[(((size_t)dg * NK + k2) * 32 + pg) * 32 + dl], u.b.accB[k2 * PAD + dl]);
      }
      if (dg == 0 && t < NK)
        cstore(&pcnt[(size_t)pg * NK + t], (float)cntB[t]);
    }
    gbar(flags, grep, gen); ++gen;

    // ---- phase C: 256 blocks = 128 clusters x 2 D-halves -> version it+1 ----
    {
      const int k = b >> 1, hh2 = b & 1;
      const int dwh = t & 127, pch = t >> 7;   // dim-in-half [0,128), pgroup chunk [0,8)
      const int dgc = hh2 * 4 + (dwh >> 5), dlc = dwh & 31;
      float s = 0.f;
#pragma unroll
      for (int p2 = pch * 4; p2 < pch * 4 + 4; ++p2)
        s += cload(&psum[(((size_t)dgc * NK + k) * 32 + p2) * 32 + dlc]);
      u.c.red4[pch * 128 + dwh] = s;
      float cv = (t < 32) ? cload(&pcnt[(size_t)t * NK + k]) : 0.f;
      if (t < 64) {
#pragma unroll
        for (int m = 1; m < 32; m <<= 1) cv += __shfl_xor(cv, m, 64);
      }
      if (t == 0) cntsh = cv;
      __syncthreads();
      float eff = 0.f;
      if (t < 128) {
        float ssum = 0.f;
#pragma unroll
        for (int ww = 0; ww < 8; ++ww) ssum += u.c.red4[ww * 128 + t];
        float mean = ssum / cntsh;        // NaN if empty, as ref
        unsigned short hh = f2bf(mean);
        unsigned short ll = f2bf(mean - bf2f(hh));
        hsm[t] = hh; lsm[t] = ll;
        eff = bf2f(hh) + bf2f(ll);
      }
      __syncthreads();                    // red4 reads + hsm/lsm writes done
      u.c.redcn[t] = (t < 128) ? eff * eff : 0.f;
      if (t < 64) {
        ull_t wv = (ull_t)hsm[2 * t] | ((ull_t)lsm[2 * t] << 16)
                 | ((ull_t)hsm[2 * t + 1] << 32) | ((ull_t)lsm[2 * t + 1] << 48);
        cstore64(&cpkW[(size_t)k * 128 + hh2 * 64 + t], wv);
      }
      __syncthreads();
      for (int st = 512; st > 0; st >>= 1) { if (t < st) u.c.redcn[t] += u.c.redcn[t + st]; __syncthreads(); }
      if (t == 0) cstore(&cn2W[k * 2 + hh2], u.c.redcn[0]);
    }
    gbar(flags, grep, gen); ++gen;
  }

  // ---------------- final: loss (log-softmax + CE), deterministic reduce ----------------
  {
    f4v acc[2][2];
    gemm_core(xhR, xlR, u, cns, t,
              cpkv + (size_t)NITER * (NK * 128), cn2v + (size_t)NITER * (NK * 2), acc);
#pragma unroll
    for (int i = 0; i < 2; ++i) {
#pragma unroll
      for (int r = 0; r < 4; ++r) {
        int prow = wr * 32 + i * 16 + g * 4 + r;
        float m = -1e30f;
#pragma unroll
        for (int j = 0; j < 2; ++j) m = fmaxf(m, acc[i][j][r]);
#pragma unroll
        for (int msk = 1; msk < 16; msk <<= 1) m = fmaxf(m, __shfl_xor(m, msk, 64));
        if (lr == 0) redd[prow * 4 + wc] = m;
      }
    }
    __syncthreads();
    if (t < NK) {
      float m = redd[t * 4];
#pragma unroll
      for (int q = 1; q < 4; ++q) m = fmaxf(m, redd[t * 4 + q]);
      gmaxs[t] = m;
      labis[t] = cloadi(&ids[pbase + t]);
    }
    __syncthreads();
#pragma unroll
    for (int i = 0; i < 2; ++i) {
#pragma unroll
      for (int r = 0; r < 4; ++r) {
        int prow = wr * 32 + i * 16 + g * 4 + r;
        float m = gmaxs[prow];
        int lab = labis[prow];
        float s = 0.f;
#pragma unroll
        for (int j = 0; j < 2; ++j) {
          int col = wc * 32 + j * 16 + lr;
          float v = acc[i][j][r];
          s += expf(v - m);
          if (col == lab) labvs[prow] = v;
        }
#pragma unroll
        for (int msk = 1; msk < 16; msk <<= 1) s += __shfl_xor(s, msk, 64);
        if (lr == 0) redd[prow * 4 + wc] = s;
      }
    }
    __syncthreads();
    if (t < NK) {
      float se = redd[t * 4] + redd[t * 4 + 1] + redd[t * 4 + 2] + redd[t * 4 + 3];
      float lse = gmaxs[t] + logf(se);
      gmaxs[t] = lse - labvs[t];
    }
    __syncthreads();
    if (t == 0) {
      float tot = 0.f;
      for (int q = 0; q < NK; ++q) tot += gmaxs[q];
      cstore(&outp[b], tot);
    }
  }
  gbar(flags, grep, gen); ++gen;
  if (b == 0) {
    u.c.redcn[t] = (t < NBLK) ? cload(&outp[t]) : 0.f;
    __syncthreads();
    for (int s = 512; s > 0; s >>= 1) { if (t < s) u.c.redcn[t] += u.c.redcn[t + s]; __syncthreads(); }
    if (t == 0) out[0] = u.c.redcn[0] * (1.0f / (float)NPTS);
  }
}

extern "C" void kernel_launch(void* const* d_in, const int* in_sizes, int n_in,
                              void* d_out, int out_size, void* d_ws, size_t ws_size,
                              hipStream_t stream) {
  const float* x        = (const float*)d_in[0];
  const int*   init_idx = (const int*)d_in[1];
  float* out = (float*)d_out;
  char* ws = (char*)d_ws;

  // ws layout (bytes):
  ull_t* cpkv = (ull_t*)(ws);                         // 101 * 131072 = 13238272
  float* cn2v = (float*)(ws + 13238272);              // 101 * 1024 = 103424
  int*   ids  = (int*)(ws + 13341696);                // 131072
  float* psum = (float*)(ws + 13472768);              // 8*128*32*32*4 = 4194304
  float* pcnt = (float*)(ws + 17667072);              // 32*128*4 = 16384
  float* outp = (float*)(ws + 17683456);              // 1024
  unsigned* flags = (unsigned*)(ws + 17684480);       // 256*64B = 16384
  unsigned* grep  = (unsigned*)(ws + 17700864);       // 64*64B = 4096

  // reset barrier state every launch (graph replays include this node)
  hipMemsetAsync(flags, 0, 20480, stream);
  kmeans_fused<<<dim3(NBLK), dim3(NTHR), 0, stream>>>(
      x, init_idx, cpkv, cn2v, ids, psum, pcnt, outp, flags, grep, out);
}